// Round 11
// baseline (889.230 us; speedup 1.0000x reference)
//
#include <hip/hip_runtime.h>

// ---------------------------------------------------------------------------
// VGAE encoder, MI355X. Two adj (16384^2 f32, 1 GiB) GEMMs dominate.
// Split-bf16 (hi+lo, 3 MFMA terms) for fp32 accuracy on the bf16 matrix core.
// R1-R10 invariant: every 2D-tiled f32 adj read schedule = ~3.1 TB/s (half of
// the chip's demonstrated 6.3-6.5 TB/s linear streams), invariant to burst
// size (256B-1KB), M (32-128), occupancy (1-4 blk/CU), prefetch depth, order.
// Burst length is capped ~1KB by LDS tile geometry -> can't get longer bursts.
// R11: make PASS 2 LINEAR. S2 (pass 1) additionally stores its in-register
// bf16 hi/lo tiles to adjT (1 GiB) in exactly S4's swizzled LDS-image layout,
// contiguous per (row-tile, K-macro). S4 reads adjT as one contiguous 64KB
// chunk per macro (copy pattern), zero cvt VALU. Also fixes R10's
// launch_bounds-induced spill (cap 256 now).
// ---------------------------------------------------------------------------

typedef __bf16 bf16_t;
typedef __attribute__((ext_vector_type(4))) __bf16 bf16x4;
typedef __attribute__((ext_vector_type(8))) __bf16 bf16x8;
typedef __attribute__((ext_vector_type(16))) float f32x16;
typedef __attribute__((ext_vector_type(4)))  float f32x4;

#define N_NODES 16384
#define MFMA3(ACC, A, B) \
    ACC = __builtin_amdgcn_mfma_f32_32x32x16_bf16(A, B, ACC, 0, 0, 0)

// Fragment layout for the B operand of mfma_f32_32x32x16_bf16:
// element (k=r, col=c) -> 1KiB units indexed by (K16 = r>>4, cblk = c>>5),
// within a unit: lane = (c&31) + 32*((r>>3)&1) holds 8 bf16 (k = ..8g..8g+7).
__device__ __forceinline__ int frag_off(int r, int c) {
    int K16  = r >> 4;
    int cblk = c >> 5;
    int g    = (r >> 3) & 1;
    int lane = (c & 31) + (g << 5);
    return ((K16 * 4 + cblk) << 9) + (lane << 3) + (r & 7);
}

__device__ __forceinline__ float4 relu_add4(float4 a, float4 b) {
    float4 r;
    r.x = fmaxf(a.x + b.x, 0.f); r.y = fmaxf(a.y + b.y, 0.f);
    r.z = fmaxf(a.z + b.z, 0.f); r.w = fmaxf(a.w + b.w, 0.f);
    return r;
}

// ---------------------------------------------------------------------------
// Small fp32 GEMM producer: out = A[16384][K] @ W[K][128]; epilogue splits
// each output into bf16 hi/lo and scatters into the fragment layout.
// ADD2: A := relu(A + A2) elementwise (fused partial-reduce of the hidden).
// ---------------------------------------------------------------------------
template<int K, bool FUSED, bool ADD2>
__global__ __launch_bounds__(256)
void producer_kernel(const float* __restrict__ A,
                     const float* __restrict__ A2,
                     const float* __restrict__ W,
                     const float* __restrict__ Wa,
                     const float* __restrict__ Wb,
                     bf16_t* __restrict__ Bh,
                     bf16_t* __restrict__ Bl)
{
    __shared__ float As[32][128];   // k-major A tile: As[k][r]
    __shared__ float Wsh[32][128];  // Wsh[k][c]
    const int t    = threadIdx.x;
    const int row0 = blockIdx.x * 128;
    const int tc   = t & 15, tr = t >> 4;   // 16x16 thread grid, 8x8 outs each

    float acc[8][8];
    #pragma unroll
    for (int i = 0; i < 8; ++i)
        #pragma unroll
        for (int j = 0; j < 8; ++j) acc[i][j] = 0.f;

    const int ra = t >> 1, ks = (t & 1) << 4;   // A staging: 16 f32/thread
    const int wk = t >> 3, wc = (t & 7) << 4;   // W staging: 16 f32/thread

    for (int k0 = 0; k0 < K; k0 += 32) {
        const float* ap = A + (size_t)(row0 + ra) * K + k0 + ks;
        float4 a0 = *(const float4*)(ap);
        float4 a1 = *(const float4*)(ap + 4);
        float4 a2 = *(const float4*)(ap + 8);
        float4 a3 = *(const float4*)(ap + 12);
        if (ADD2) {
            const float* ap2 = A2 + (size_t)(row0 + ra) * K + k0 + ks;
            a0 = relu_add4(a0, *(const float4*)(ap2));
            a1 = relu_add4(a1, *(const float4*)(ap2 + 4));
            a2 = relu_add4(a2, *(const float4*)(ap2 + 8));
            a3 = relu_add4(a3, *(const float4*)(ap2 + 12));
        }
        float4 w0, w1, w2, w3;
        if (!FUSED) {
            const float* wp = W + (size_t)(k0 + wk) * 128 + wc;
            w0 = *(const float4*)(wp);     w1 = *(const float4*)(wp + 4);
            w2 = *(const float4*)(wp + 8); w3 = *(const float4*)(wp + 12);
        } else {
            const float* wp = (wc < 64) ? (Wa + (size_t)(k0 + wk) * 64 + wc)
                                        : (Wb + (size_t)(k0 + wk) * 64 + (wc - 64));
            w0 = *(const float4*)(wp);     w1 = *(const float4*)(wp + 4);
            w2 = *(const float4*)(wp + 8); w3 = *(const float4*)(wp + 12);
        }
        __syncthreads();   // previous iteration's compute done before overwrite
        {
            float tmp[16] = {a0.x,a0.y,a0.z,a0.w, a1.x,a1.y,a1.z,a1.w,
                             a2.x,a2.y,a2.z,a2.w, a3.x,a3.y,a3.z,a3.w};
            #pragma unroll
            for (int j = 0; j < 16; ++j) As[ks + j][ra] = tmp[j];
            *(float4*)&Wsh[wk][wc     ] = w0;
            *(float4*)&Wsh[wk][wc +  4] = w1;
            *(float4*)&Wsh[wk][wc +  8] = w2;
            *(float4*)&Wsh[wk][wc + 12] = w3;
        }
        __syncthreads();
        #pragma unroll 4
        for (int k = 0; k < 32; ++k) {
            float av[8], wv[8];
            *(float4*)&av[0] = *(const float4*)&As[k][8 * tr];
            *(float4*)&av[4] = *(const float4*)&As[k][8 * tr + 4];
            *(float4*)&wv[0] = *(const float4*)&Wsh[k][8 * tc];
            *(float4*)&wv[4] = *(const float4*)&Wsh[k][8 * tc + 4];
            #pragma unroll
            for (int i = 0; i < 8; ++i)
                #pragma unroll
                for (int j = 0; j < 8; ++j)
                    acc[i][j] = fmaf(av[i], wv[j], acc[i][j]);
        }
    }

    #pragma unroll
    for (int i = 0; i < 8; ++i) {
        int r = row0 + 8 * tr + i;
        #pragma unroll
        for (int j = 0; j < 8; ++j) {
            int c = 8 * tc + j;
            float v = acc[i][j];
            bf16_t h = (bf16_t)v;
            bf16_t l = (bf16_t)(v - (float)h);
            int off = frag_off(r, c);
            Bh[off] = h;
            Bl[off] = l;
        }
    }
}

// ---------------------------------------------------------------------------
// PASS 1 (S2): P_kh = adj[128-row tile, kh-half] @ B[kh-half]  AND stream the
// in-register hi/lo tiles to adjT in S4's image layout.
// grid 256 (128 mt x 2 kh), 512 thr (8 waves = 2 row-half x 4 col-quadrant,
// 2 stacked 32x32 tiles each). 32 macros of K=256; single-buffer LDS
// [128][256] hi+lo = 128KB. adj: wave w stages rows w*16..+15, 1KB dwordx4
// bursts. adjT image (64 rows x 256 k, 64KB: h 32KB | l 32KB), element (r,c)
// at byte r*512 + (((c>>4)^(r&15))<<5) + (c&15)*2 -- the swizzled LDS image.
// Image index = mt2*64 + kh*32 + m,  mt2 = 2*mt + (row>=64).
// ---------------------------------------------------------------------------
struct BSet { bf16x8 h[4]; bf16x8 l[4]; };   // 32 VGPRs

__global__ __launch_bounds__(512)
void adj_gemm_store_kernel(const float* __restrict__ adj,
                           const bf16_t* __restrict__ Bh,
                           const bf16_t* __restrict__ Bl,
                           float* __restrict__ P0,
                           float* __restrict__ P1,
                           bf16_t* __restrict__ adjT)
{
    __shared__ __align__(16) bf16_t AsH[128 * 256];
    __shared__ __align__(16) bf16_t AsL[128 * 256];
    const int t    = threadIdx.x;
    const int lane = t & 63;
    const int w    = t >> 6;
    const int mt   = blockIdx.x >> 1;
    const int kh   = blockIdx.x & 1;
    const int row0 = mt << 7;
    const int hi32 = lane >> 5;
    float* const outP = kh ? P1 : P0;

    // adj staging: wave w stages rows w*16+j (j=0..15), 1KB burst per row.
    const float* aBase = adj + (size_t)(row0 + (w << 4)) * 16384
                             + (kh << 13) + (lane << 2);

    // LDS write indices (elems) + adjT store offsets (bytes)
    int wIdx[16], stOff[16];
    #pragma unroll
    for (int j = 0; j < 16; ++j) {
        int row = (w << 4) + j;
        wIdx[j] = (row << 8) + ((((lane >> 2) ^ (row & 15)) << 4)
                                + ((lane & 3) << 2));
        int rl = row & 63;
        stOff[j] = (rl << 9) + ((((lane >> 2) ^ (rl & 15)) << 5)
                                + ((lane & 3) << 3));
    }
    const int mt2 = 2 * mt + (w >> 2 >= 1 ? (w >= 4 ? 1 : 0) : 0);  // w>=4
    char* const stBase = (char*)adjT
                       + (((size_t)(2 * mt + (w >= 4)) * 64 + kh * 32) << 16);

    // A-frag reads: wave = (row-half rh = w>>2, col-quadrant cq = w&3)
    const int rh   = w >> 2, cq = w & 3;
    const int frow = (rh << 6) + (lane & 31);
    const int rbase0 = (frow << 8) + (hi32 << 3);
    const int rbase1 = ((frow + 32) << 8) + (hi32 << 3);
    const int rx     = frow & 15;

    const int tb   = (cq << 9) + (lane << 3);
    const int sub0 = kh << 7;

    f32x16 acc0, acc1;
    #pragma unroll
    for (int i = 0; i < 16; ++i) { acc0[i] = 0.f; acc1[i] = 0.f; }

    f32x4 ar[16];
    BSet S0, S1;

    auto loadAdj = [&](int mac) {
        const float* p = aBase + (mac << 8);
        #pragma unroll
        for (int j = 0; j < 16; ++j)
            ar[j] = __builtin_nontemporal_load((const f32x4*)(p + (size_t)j * 16384));
    };
    auto cvtWrite = [&](int mac) {
        char* const sp = stBase + ((size_t)mac << 16);
        #pragma unroll
        for (int j = 0; j < 16; ++j) {
            bf16x4 hv, lv;
            #pragma unroll
            for (int e = 0; e < 4; ++e) {
                float v = ar[j][e];
                bf16_t h = (bf16_t)v;
                hv[e] = h;
                lv[e] = (bf16_t)(v - (float)h);
            }
            *(bf16x4*)&AsH[wIdx[j]] = hv;
            *(bf16x4*)&AsL[wIdx[j]] = lv;
            __builtin_nontemporal_store(hv, (bf16x4*)(sp + stOff[j]));
            __builtin_nontemporal_store(lv, (bf16x4*)(sp + stOff[j] + 32768));
        }
    };
    auto loadB = [&](BSet& S, int sub) {
        const size_t base = ((size_t)sub << 13) + tb;
        #pragma unroll
        for (int s = 0; s < 4; ++s) {
            S.h[s] = *(const bf16x8*)(Bh + base + (s << 11));
            S.l[s] = *(const bf16x8*)(Bl + base + (s << 11));
        }
    };
    auto computeS = [&](const BSet& S, int s) {
        #pragma unroll
        for (int k16 = 0; k16 < 4; ++k16) {
            const int u  = (s << 2) + k16;
            const int o  = (u ^ rx) << 4;
            bf16x8 ah0 = *(const bf16x8*)&AsH[rbase0 + o];
            bf16x8 al0 = *(const bf16x8*)&AsL[rbase0 + o];
            bf16x8 ah1 = *(const bf16x8*)&AsH[rbase1 + o];
            bf16x8 al1 = *(const bf16x8*)&AsL[rbase1 + o];
            MFMA3(acc0, ah0, S.h[k16]);
            MFMA3(acc1, ah1, S.h[k16]);
            MFMA3(acc0, ah0, S.l[k16]);
            MFMA3(acc1, ah1, S.l[k16]);
            MFMA3(acc0, al0, S.h[k16]);
            MFMA3(acc1, al1, S.h[k16]);
        }
    };

#define SYNC_LDS() do { asm volatile("s_waitcnt lgkmcnt(0)" ::: "memory"); \
                        __builtin_amdgcn_s_barrier(); } while (0)

    loadAdj(0);
    for (int m = 0; m < 32; ++m) {
        cvtWrite(m);                         // waits ar = adj(m); also stores
        SYNC_LDS();
        const int sb = sub0 + (m << 2);
        loadB(S0, sb + 0);
        if (m < 31) loadAdj(m + 1);
        computeS(S0, 0);
        loadB(S1, sb + 1);  computeS(S1, 1);
        loadB(S0, sb + 2);  computeS(S0, 2);
        loadB(S1, sb + 3);  computeS(S1, 3);
        SYNC_LDS();
    }
#undef SYNC_LDS

    const int col = (cq << 5) + (lane & 31);
    const int rw  = row0 + (rh << 6) + (hi32 << 2);
    #pragma unroll
    for (int q = 0; q < 16; ++q) {
        int r = rw + (q & 3) + ((q >> 2) << 3);
        outP[(size_t)r * 128 + col]        = acc0[q];
        outP[(size_t)(r + 32) * 128 + col] = acc1[q];
    }
}

// ---------------------------------------------------------------------------
// PASS 2 (S4): T = adj @ B2 read from the pre-tiled adjT.  grid 256 (block =
// mt2, rows mt2*64), 512 thr, 64 macros of K=256, full K. Per macro the block
// reads ONE CONTIGUOUS 64KB image (linear copy pattern), stages to LDS via
// reg round-trip (thread t: 8 x 16B at byte t*16 + round*8192), zero cvt.
// Consumption identical to pass 1 (same swizzled image).
// ---------------------------------------------------------------------------
__global__ __launch_bounds__(512)
void adj_gemm2_kernel(const bf16_t* __restrict__ adjT,
                      const bf16_t* __restrict__ Bh,
                      const bf16_t* __restrict__ Bl,
                      float* __restrict__ T)
{
    __shared__ __align__(16) bf16_t As[32768];   // h 16384 elems | l 16384
    const int t    = threadIdx.x;
    const int lane = t & 63;
    const int w    = t >> 6;
    const int mt2  = blockIdx.x;
    const int row0 = mt2 << 6;
    const int hi32 = lane >> 5;

    const char* const src0 = (const char*)adjT + ((size_t)mt2 << 22);  // *64*65536

    const int rh   = w >> 2, cq = w & 3;
    const int frow = (rh << 5) + (lane & 31);
    const int rbase = (frow << 8) + (hi32 << 3);
    const int rx    = frow & 15;

    const int tb = (cq << 9) + (lane << 3);

    f32x16 acc;
    #pragma unroll
    for (int i = 0; i < 16; ++i) acc[i] = 0.f;

    bf16x8 st[8];
    BSet S0, S1;

    auto loadSt = [&](int mac) {
        const char* p = src0 + ((size_t)mac << 16) + (t << 4);
        #pragma unroll
        for (int r = 0; r < 8; ++r)
            st[r] = __builtin_nontemporal_load((const bf16x8*)(p + r * 8192));
    };
    auto dsWriteSt = [&]() {
        #pragma unroll
        for (int r = 0; r < 8; ++r)
            *(bf16x8*)((char*)As + (t << 4) + r * 8192) = st[r];
    };
    auto loadB = [&](BSet& S, int sub) {
        const size_t base = ((size_t)sub << 13) + tb;
        #pragma unroll
        for (int s = 0; s < 4; ++s) {
            S.h[s] = *(const bf16x8*)(Bh + base + (s << 11));
            S.l[s] = *(const bf16x8*)(Bl + base + (s << 11));
        }
    };
    auto computeS = [&](const BSet& S, int s) {
        #pragma unroll
        for (int k16 = 0; k16 < 4; ++k16) {
            const int u  = (s << 2) + k16;
            const int o  = (u ^ rx) << 4;
            bf16x8 ah = *(const bf16x8*)&As[rbase + o];
            bf16x8 al = *(const bf16x8*)&As[rbase + o + 16384];
            MFMA3(acc, ah, S.h[k16]);
            MFMA3(acc, ah, S.l[k16]);
            MFMA3(acc, al, S.h[k16]);
        }
    };

#define SYNC_LDS() do { asm volatile("s_waitcnt lgkmcnt(0)" ::: "memory"); \
                        __builtin_amdgcn_s_barrier(); } while (0)

    loadSt(0);
    for (int m = 0; m < 64; ++m) {
        dsWriteSt();                         // waits st = image(m)
        SYNC_LDS();
        const int sb = m << 2;
        loadB(S0, sb + 0);
        if (m < 63) loadSt(m + 1);           // linear 64KB, in flight
        computeS(S0, 0);
        loadB(S1, sb + 1);  computeS(S1, 1);
        loadB(S0, sb + 2);  computeS(S0, 2);
        loadB(S1, sb + 3);  computeS(S1, 3);
        SYNC_LDS();
    }
#undef SYNC_LDS

    const int col = (cq << 5) + (lane & 31);
    const int rw  = row0 + (rh << 5) + (hi32 << 2);
    #pragma unroll
    for (int q = 0; q < 16; ++q) {
        int r = rw + (q & 3) + ((q >> 2) << 3);
        T[(size_t)r * 128 + col] = acc[q];
    }
}

// ---------------------------------------------------------------------------
// Final: mean = Z@Wp + bp; out = noise*exp(min(logstd,10)) + mean
// T = [Z | logstd] as [16384][128] f32
// ---------------------------------------------------------------------------
__global__ __launch_bounds__(256)
void final_kernel(const float* __restrict__ T,
                  const float* __restrict__ Wp,
                  const float* __restrict__ bp,
                  const float* __restrict__ noise,
                  float* __restrict__ out)
{
    __shared__ float Wps[64][64];
    __shared__ float Ts[64][64];
    const int t = threadIdx.x;
    const int row0 = blockIdx.x * 64;
    {
        int k = t >> 2, c0 = (t & 3) << 4;
        #pragma unroll
        for (int i = 0; i < 4; ++i)
            *(float4*)&Wps[k][c0 + 4 * i] = *(const float4*)&Wp[(size_t)k * 64 + c0 + 4 * i];
        #pragma unroll
        for (int i = 0; i < 4; ++i)
            *(float4*)&Ts[k][c0 + 4 * i] =
                *(const float4*)&T[(size_t)(row0 + k) * 128 + c0 + 4 * i];
    }
    __syncthreads();

    const int r  = t >> 2;
    const int c0 = (t & 3) << 4;
    float acc[16];
    #pragma unroll
    for (int j = 0; j < 16; ++j) acc[j] = bp[c0 + j];
    for (int k = 0; k < 64; ++k) {
        float a = Ts[r][k];
        #pragma unroll
        for (int j = 0; j < 16; ++j) acc[j] = fmaf(a, Wps[k][c0 + j], acc[j]);
    }
    const int grow = row0 + r;
    #pragma unroll
    for (int j = 0; j < 16; ++j) {
        float ls = T[(size_t)grow * 128 + 64 + c0 + j];
        ls = fminf(ls, 10.0f);
        out[(size_t)grow * 64 + c0 + j] =
            noise[(size_t)grow * 64 + c0 + j] * __expf(ls) + acc[j];
    }
}

// ---------------------------------------------------------------------------
extern "C" void kernel_launch(void* const* d_in, const int* in_sizes, int n_in,
                              void* d_out, int out_size, void* d_ws, size_t ws_size,
                              hipStream_t stream) {
    const float* X     = (const float*)d_in[0];
    const float* adj   = (const float*)d_in[1];
    const float* W1    = (const float*)d_in[2];
    const float* Wm    = (const float*)d_in[3];
    const float* Wsv   = (const float*)d_in[4];
    const float* Wp    = (const float*)d_in[5];
    const float* bp    = (const float*)d_in[6];
    const float* noise = (const float*)d_in[7];
    float* out = (float*)d_out;

    char* ws = (char*)d_ws;
    bf16_t* Bh   = (bf16_t*)ws;                    // 4 MB
    bf16_t* Bl   = (bf16_t*)(ws + (4u << 20));     // 4 MB
    float*  P0   = (float*)(ws + (8u << 20));      // 8 MB partial (kh=0) / T
    float*  P1   = (float*)(ws + (16u << 20));     // 8 MB partial (kh=1)
    bf16_t* adjT = (bf16_t*)(ws + (24u << 20));    // 1 GiB pre-tiled hi/lo adj

    // S1: B1 = fragsplit((X @ W1)^T)
    producer_kernel<256, false, false><<<128, 256, 0, stream>>>(
        X, nullptr, W1, nullptr, nullptr, Bh, Bl);
    // S2: hidden partials P_kh = adj[:,kh] @ B1[kh]; adjT := tiled bf16 adj
    adj_gemm_store_kernel<<<256, 512, 0, stream>>>(adj, Bh, Bl, P0, P1, adjT);
    // S3: B2 = fragsplit((relu(P0+P1) @ [Wm|Ws])^T)
    producer_kernel<128, true, true><<<128, 256, 0, stream>>>(
        P0, P1, nullptr, Wm, Wsv, Bh, Bl);
    // S4: T = adj @ HW from linear adjT  (writes into P0 as T)
    adj_gemm2_kernel<<<256, 512, 0, stream>>>(adjT, Bh, Bl, P0);
    // S5: epilogue
    final_kernel<<<256, 256, 0, stream>>>(P0, Wp, bp, noise, out);
}

// Round 12
// 795.399 us; speedup vs baseline: 1.1180x; 1.1180x over previous
//
#include <hip/hip_runtime.h>

// ---------------------------------------------------------------------------
// VGAE encoder, MI355X. Two adj (16384^2 f32, 1 GiB) GEMMs dominate.
// Split-bf16 (hi+lo, 3 MFMA terms) for fp32 accuracy on the bf16 matrix core.
// R1-R11: every register-staged adj read schedule = ~3.1 TB/s, invariant to
// pattern/granularity/M/occupancy/depth/order (R11 proved linear==tiled).
// Common factor: register-destined loads + in-order vmcnt coupling.
// R12: adopt the m97 primitive -- __builtin_amdgcn_global_load_lds (width 16)
// for adj: HBM -> LDS direct, no VGPR round-trip; ONE explicit counted
// vmcnt(0) per macro placed so compute's B-waits never force the gload
// (issue order: loadB, gload(m+1), compute). Per-wave cvt phase splits f32
// -> bf16 hi/lo into swizzled arrays. M=32, splitK2, grid 1024 = 4 blk/CU,
// Kmacro=128, LDS 32KB (Fst 16 + AsH 8 + AsL 8).
// ---------------------------------------------------------------------------

typedef __bf16 bf16_t;
typedef __attribute__((ext_vector_type(4))) __bf16 bf16x4;
typedef __attribute__((ext_vector_type(8))) __bf16 bf16x8;
typedef __attribute__((ext_vector_type(16))) float f32x16;
typedef __attribute__((ext_vector_type(4)))  float f32x4;

#define N_NODES 16384
#define MFMA3(ACC, A, B) \
    ACC = __builtin_amdgcn_mfma_f32_32x32x16_bf16(A, B, ACC, 0, 0, 0)

#define GLOAD16(gp, lp) __builtin_amdgcn_global_load_lds(                    \
    (const __attribute__((address_space(1))) unsigned int*)(gp),             \
    (__attribute__((address_space(3))) unsigned int*)(lp), 16, 0, 0)

// Fragment layout for the B operand of mfma_f32_32x32x16_bf16:
// element (k=r, col=c) -> 1KiB units indexed by (K16 = r>>4, cblk = c>>5),
// within a unit: lane = (c&31) + 32*((r>>3)&1) holds 8 bf16 (k = ..8g..8g+7).
__device__ __forceinline__ int frag_off(int r, int c) {
    int K16  = r >> 4;
    int cblk = c >> 5;
    int g    = (r >> 3) & 1;
    int lane = (c & 31) + (g << 5);
    return ((K16 * 4 + cblk) << 9) + (lane << 3) + (r & 7);
}

__device__ __forceinline__ float4 relu_add4(float4 a, float4 b) {
    float4 r;
    r.x = fmaxf(a.x + b.x, 0.f); r.y = fmaxf(a.y + b.y, 0.f);
    r.z = fmaxf(a.z + b.z, 0.f); r.w = fmaxf(a.w + b.w, 0.f);
    return r;
}

// ---------------------------------------------------------------------------
// Small fp32 GEMM producer: out = A[16384][K] @ W[K][128]; epilogue splits
// each output into bf16 hi/lo and scatters into the fragment layout.
// ADD2: A := relu(A + A2) elementwise (fused partial-reduce of the hidden).
// ---------------------------------------------------------------------------
template<int K, bool FUSED, bool ADD2>
__global__ __launch_bounds__(256)
void producer_kernel(const float* __restrict__ A,
                     const float* __restrict__ A2,
                     const float* __restrict__ W,
                     const float* __restrict__ Wa,
                     const float* __restrict__ Wb,
                     bf16_t* __restrict__ Bh,
                     bf16_t* __restrict__ Bl)
{
    __shared__ float As[32][128];   // k-major A tile: As[k][r]
    __shared__ float Wsh[32][128];  // Wsh[k][c]
    const int t    = threadIdx.x;
    const int row0 = blockIdx.x * 128;
    const int tc   = t & 15, tr = t >> 4;   // 16x16 thread grid, 8x8 outs each

    float acc[8][8];
    #pragma unroll
    for (int i = 0; i < 8; ++i)
        #pragma unroll
        for (int j = 0; j < 8; ++j) acc[i][j] = 0.f;

    const int ra = t >> 1, ks = (t & 1) << 4;   // A staging: 16 f32/thread
    const int wk = t >> 3, wc = (t & 7) << 4;   // W staging: 16 f32/thread

    for (int k0 = 0; k0 < K; k0 += 32) {
        const float* ap = A + (size_t)(row0 + ra) * K + k0 + ks;
        float4 a0 = *(const float4*)(ap);
        float4 a1 = *(const float4*)(ap + 4);
        float4 a2 = *(const float4*)(ap + 8);
        float4 a3 = *(const float4*)(ap + 12);
        if (ADD2) {
            const float* ap2 = A2 + (size_t)(row0 + ra) * K + k0 + ks;
            a0 = relu_add4(a0, *(const float4*)(ap2));
            a1 = relu_add4(a1, *(const float4*)(ap2 + 4));
            a2 = relu_add4(a2, *(const float4*)(ap2 + 8));
            a3 = relu_add4(a3, *(const float4*)(ap2 + 12));
        }
        float4 w0, w1, w2, w3;
        if (!FUSED) {
            const float* wp = W + (size_t)(k0 + wk) * 128 + wc;
            w0 = *(const float4*)(wp);     w1 = *(const float4*)(wp + 4);
            w2 = *(const float4*)(wp + 8); w3 = *(const float4*)(wp + 12);
        } else {
            const float* wp = (wc < 64) ? (Wa + (size_t)(k0 + wk) * 64 + wc)
                                        : (Wb + (size_t)(k0 + wk) * 64 + (wc - 64));
            w0 = *(const float4*)(wp);     w1 = *(const float4*)(wp + 4);
            w2 = *(const float4*)(wp + 8); w3 = *(const float4*)(wp + 12);
        }
        __syncthreads();   // previous iteration's compute done before overwrite
        {
            float tmp[16] = {a0.x,a0.y,a0.z,a0.w, a1.x,a1.y,a1.z,a1.w,
                             a2.x,a2.y,a2.z,a2.w, a3.x,a3.y,a3.z,a3.w};
            #pragma unroll
            for (int j = 0; j < 16; ++j) As[ks + j][ra] = tmp[j];
            *(float4*)&Wsh[wk][wc     ] = w0;
            *(float4*)&Wsh[wk][wc +  4] = w1;
            *(float4*)&Wsh[wk][wc +  8] = w2;
            *(float4*)&Wsh[wk][wc + 12] = w3;
        }
        __syncthreads();
        #pragma unroll 4
        for (int k = 0; k < 32; ++k) {
            float av[8], wv[8];
            *(float4*)&av[0] = *(const float4*)&As[k][8 * tr];
            *(float4*)&av[4] = *(const float4*)&As[k][8 * tr + 4];
            *(float4*)&wv[0] = *(const float4*)&Wsh[k][8 * tc];
            *(float4*)&wv[4] = *(const float4*)&Wsh[k][8 * tc + 4];
            #pragma unroll
            for (int i = 0; i < 8; ++i)
                #pragma unroll
                for (int j = 0; j < 8; ++j)
                    acc[i][j] = fmaf(av[i], wv[j], acc[i][j]);
        }
    }

    #pragma unroll
    for (int i = 0; i < 8; ++i) {
        int r = row0 + 8 * tr + i;
        #pragma unroll
        for (int j = 0; j < 8; ++j) {
            int c = 8 * tc + j;
            float v = acc[i][j];
            bf16_t h = (bf16_t)v;
            bf16_t l = (bf16_t)(v - (float)h);
            int off = frag_off(r, c);
            Bh[off] = h;
            Bl[off] = l;
        }
    }
}

// ---------------------------------------------------------------------------
// Big kernel: P_kh = adj[rows, kh-half] @ B[kh-half], M-tile 32, K-half 8192.
// grid 1024 (512 mt x 2 kh) = 4 blocks/CU, 256 thr (4 waves = 4 B
// col-quadrants). 64 macros of K=128.
// Staging: global_load_lds width16 adj f32 -> linear Fst[32][128] (16KB,
// single buffer; wave w owns rows w*8..w*8+7, 4 insts of 1KB each).
// cvt phase (per-wave, own rows only -> no extra barrier): f32 -> bf16 hi/lo
// into AsH/AsL with 16B-granule XOR swizzle: granule g of row r stored at
// byte r*256 + ((g ^ (r&15))<<4)   (g = k>>3, 16 granules/row).
// Macro: [vmcnt(0): adj(m) landed] cvt -> SYNC -> loadB S0,S1 -> gload(m+1)
// -> compute (B-waits leave <=4 outstanding: gload unforced, full-macro
// lead) -> SYNC. Latency residue hidden by 4-block TLP.
// ---------------------------------------------------------------------------
struct BSet { bf16x8 h[4]; bf16x8 l[4]; };   // 32 VGPRs

__global__ __launch_bounds__(256, 4)
void adj_gemm_kernel(const float* __restrict__ adj,
                     const bf16_t* __restrict__ Bh,
                     const bf16_t* __restrict__ Bl,
                     float* __restrict__ P0,
                     float* __restrict__ P1)
{
    __shared__ __align__(16) float  Fst[32 * 128];   // 16KB raw f32 tile
    __shared__ __align__(16) bf16_t AsH[32 * 128];   // 8KB
    __shared__ __align__(16) bf16_t AsL[32 * 128];   // 8KB
    const int t    = threadIdx.x;
    const int lane = t & 63;
    const int w    = t >> 6;                 // wave = B col-quadrant
    const int mt   = blockIdx.x >> 1;
    const int kh   = blockIdx.x & 1;
    const int row0 = mt << 5;
    const int hi32 = lane >> 5;
    float* const outP = kh ? P1 : P0;

    // gload source: inst j covers rows w*8+2j (lanes 0-31) / +1 (lanes 32-63)
    const char* gB = (const char*)adj
                   + ((size_t)(row0 + (w << 3) + hi32) << 16)   // row * 65536B
                   + (kh << 15) + ((lane & 31) << 4);
    // LDS dest per j (wave-uniform): Fst byte (w*8+2j)*512

    const int fr = lane & 31, rx = fr & 15;
    const int tb = (w << 9) + (lane << 3);   // B frag per-thread base (elems)

    f32x16 acc;
    #pragma unroll
    for (int i = 0; i < 16; ++i) acc[i] = 0.f;

    BSet S0, S1;

    auto gload = [&](int mac) {
        const char* p = gB + ((size_t)mac << 9);
        #pragma unroll
        for (int j = 0; j < 4; ++j)
            GLOAD16(p + ((size_t)j << 17),
                    (char*)Fst + (((w << 3) + 2 * j) << 9));
    };
    auto cvt = [&]() {
        #pragma unroll
        for (int p = 0; p < 4; ++p) {
            const int b = (w << 12) + (p << 10) + (lane << 4);
            f32x4 v = *(const f32x4*)((const char*)Fst + b);
            const int r    = (w << 3) + 2 * p + hi32;
            const int g    = (lane & 31) >> 1;
            const int half = lane & 1;
            const int ob   = (r << 8) + (((g ^ (r & 15)) << 4) + (half << 3));
            bf16x4 hv, lv;
            #pragma unroll
            for (int e = 0; e < 4; ++e) {
                float x = v[e];
                bf16_t h = (bf16_t)x;
                hv[e] = h;
                lv[e] = (bf16_t)(x - (float)h);
            }
            *(bf16x4*)((char*)AsH + ob) = hv;
            *(bf16x4*)((char*)AsL + ob) = lv;
        }
    };
    auto loadB = [&](BSet& S, int sub) {
        const size_t base = ((size_t)sub << 13) + tb;
        #pragma unroll
        for (int s = 0; s < 4; ++s) {
            S.h[s] = *(const bf16x8*)(Bh + base + (s << 11));
            S.l[s] = *(const bf16x8*)(Bl + base + (s << 11));
        }
    };
    auto computeS = [&](const BSet& S, int s) {
        #pragma unroll
        for (int k16 = 0; k16 < 4; ++k16) {
            const int u  = (s << 2) + k16;
            const int ob = (fr << 8) + (((((u << 1) + hi32) ^ rx)) << 4);
            bf16x8 ah = *(const bf16x8*)((const char*)AsH + ob);
            bf16x8 al = *(const bf16x8*)((const char*)AsL + ob);
            MFMA3(acc, ah, S.h[k16]);
            MFMA3(acc, ah, S.l[k16]);
            MFMA3(acc, al, S.h[k16]);
        }
    };

    // lgkm-only barrier: ds ops drained; outstanding gloads (counted by
    // vmcnt) stay in flight across the barrier.
#define SYNC_LDS() do { asm volatile("s_waitcnt lgkmcnt(0)" ::: "memory"); \
                        __builtin_amdgcn_s_barrier(); } while (0)

    gload(0);
    for (int m = 0; m < 64; ++m) {
        asm volatile("s_waitcnt vmcnt(0)" ::: "memory");   // adj(m) in Fst
        cvt();                       // own rows only: no barrier needed first
        SYNC_LDS();                  // swizzled tile visible to all waves
        const int sb = (kh << 7) + (m << 1);
        loadB(S0, sb);
        loadB(S1, sb + 1);
        if (m < 63) gload(m + 1);    // issued AFTER B: compute's B-waits
                                     // leave gloads in flight (full lead)
        computeS(S0, 0);
        computeS(S1, 1);
        SYNC_LDS();                  // reads done before next cvt overwrite
    }
#undef SYNC_LDS

    // C write: col = w*32 + lane&31, row = (q&3) + 8*(q>>2) + 4*hi32
    const int col = (w << 5) + (lane & 31);
    const int rb  = row0 + (hi32 << 2);
    #pragma unroll
    for (int q = 0; q < 16; ++q) {
        int r = rb + (q & 3) + ((q >> 2) << 3);
        outP[(size_t)r * 128 + col] = acc[q];
    }
}

// ---------------------------------------------------------------------------
// Final: T = T0+T1 ([16384][128], Z cols 0-63 | logstd cols 64-127);
// mean = Z@Wp + bp; out = noise*exp(min(logstd,10)) + mean
// ---------------------------------------------------------------------------
__global__ __launch_bounds__(256)
void final_kernel(const float* __restrict__ T0,
                  const float* __restrict__ T1,
                  const float* __restrict__ Wp,
                  const float* __restrict__ bp,
                  const float* __restrict__ noise,
                  float* __restrict__ out)
{
    __shared__ float Wps[64][64];
    __shared__ float Ts[64][64];
    const int t = threadIdx.x;
    const int row0 = blockIdx.x * 64;
    {
        int k = t >> 2, c0 = (t & 3) << 4;
        #pragma unroll
        for (int i = 0; i < 4; ++i)
            *(float4*)&Wps[k][c0 + 4 * i] = *(const float4*)&Wp[(size_t)k * 64 + c0 + 4 * i];
        #pragma unroll
        for (int i = 0; i < 4; ++i) {
            float4 z0 = *(const float4*)&T0[(size_t)(row0 + k) * 128 + c0 + 4 * i];
            float4 z1 = *(const float4*)&T1[(size_t)(row0 + k) * 128 + c0 + 4 * i];
            float4 zs; zs.x = z0.x + z1.x; zs.y = z0.y + z1.y;
            zs.z = z0.z + z1.z; zs.w = z0.w + z1.w;
            *(float4*)&Ts[k][c0 + 4 * i] = zs;
        }
    }
    __syncthreads();

    const int r  = t >> 2;
    const int c0 = (t & 3) << 4;
    float acc[16];
    #pragma unroll
    for (int j = 0; j < 16; ++j) acc[j] = bp[c0 + j];
    for (int k = 0; k < 64; ++k) {
        float a = Ts[r][k];
        #pragma unroll
        for (int j = 0; j < 16; ++j) acc[j] = fmaf(a, Wps[k][c0 + j], acc[j]);
    }
    const int grow = row0 + r;
    #pragma unroll
    for (int j = 0; j < 16; ++j) {
        size_t li = (size_t)grow * 128 + 64 + c0 + j;
        float ls = T0[li] + T1[li];
        ls = fminf(ls, 10.0f);
        out[(size_t)grow * 64 + c0 + j] =
            noise[(size_t)grow * 64 + c0 + j] * __expf(ls) + acc[j];
    }
}

// ---------------------------------------------------------------------------
extern "C" void kernel_launch(void* const* d_in, const int* in_sizes, int n_in,
                              void* d_out, int out_size, void* d_ws, size_t ws_size,
                              hipStream_t stream) {
    const float* X     = (const float*)d_in[0];
    const float* adj   = (const float*)d_in[1];
    const float* W1    = (const float*)d_in[2];
    const float* Wm    = (const float*)d_in[3];
    const float* Wsv   = (const float*)d_in[4];
    const float* Wp    = (const float*)d_in[5];
    const float* bp    = (const float*)d_in[6];
    const float* noise = (const float*)d_in[7];
    float* out = (float*)d_out;

    char* ws = (char*)d_ws;
    bf16_t* Bh = (bf16_t*)ws;                     // 4 MB
    bf16_t* Bl = (bf16_t*)(ws + (4u << 20));      // 4 MB
    float*  P0 = (float*)(ws + (8u << 20));       // 8 MB partial (kh=0)
    float*  P1 = (float*)(ws + (16u << 20));      // 8 MB partial (kh=1)

    // S1: B1 = fragsplit((X @ W1)^T)
    producer_kernel<256, false, false><<<128, 256, 0, stream>>>(
        X, nullptr, W1, nullptr, nullptr, Bh, Bl);
    // S2: hidden partials: P_kh = adj[:, kh-half] @ B1[kh-half]
    adj_gemm_kernel<<<1024, 256, 0, stream>>>(adj, Bh, Bl, P0, P1);
    // S3: B2 = fragsplit((relu(P0+P1) @ [Wm|Ws])^T)   (reduce+relu fused)
    producer_kernel<128, true, true><<<128, 256, 0, stream>>>(
        P0, P1, nullptr, Wm, Wsv, Bh, Bl);
    // S4: T partials
    adj_gemm_kernel<<<1024, 256, 0, stream>>>(adj, Bh, Bl, P0, P1);
    // S5: epilogue (T = P0+P1 summed on the fly)
    final_kernel<<<256, 256, 0, stream>>>(P0, P1, Wp, bp, noise, out);
}

// Round 13
// 719.092 us; speedup vs baseline: 1.2366x; 1.1061x over previous
//
#include <hip/hip_runtime.h>

// ---------------------------------------------------------------------------
// VGAE encoder, MI355X. Two adj (16384^2 f32, 1 GiB) GEMMs dominate.
// Split-bf16 (hi+lo, 3 MFMA terms) for fp32 accuracy on the bf16 matrix core.
// R1-R12 invariant: adj pass = ~345us (~3.1 TB/s) under every schedule
// (granularity/depth/order/pattern/occupancy/gload_lds). Last unfalsified
// theory: B-fragment traffic (R9: 4 GB/dispatch through L2/L3, vs adj's
// 1.07 GB HBM) contends on the fabric and binds the dispatch.
// R13: R9 exactly, but M=64 (512 thr, 8 waves, per-wave state unchanged:
// 8 staged rows, single BSet, acc 16 -> ~100 VGPR, no spill), LDS 64KB,
// grid 512 = 2 blocks/CU. Chip-wide B traffic halves: 4 GB -> 2 GB.
// ---------------------------------------------------------------------------

typedef __bf16 bf16_t;
typedef __attribute__((ext_vector_type(4))) __bf16 bf16x4;
typedef __attribute__((ext_vector_type(8))) __bf16 bf16x8;
typedef __attribute__((ext_vector_type(16))) float f32x16;
typedef __attribute__((ext_vector_type(4)))  float f32x4;

#define N_NODES 16384
#define MFMA3(ACC, A, B) \
    ACC = __builtin_amdgcn_mfma_f32_32x32x16_bf16(A, B, ACC, 0, 0, 0)

// Fragment layout for the B operand of mfma_f32_32x32x16_bf16:
// element (k=r, col=c) -> 1KiB units indexed by (K16 = r>>4, cblk = c>>5),
// within a unit: lane = (c&31) + 32*((r>>3)&1) holds 8 bf16 (k = ..8g..8g+7).
__device__ __forceinline__ int frag_off(int r, int c) {
    int K16  = r >> 4;
    int cblk = c >> 5;
    int g    = (r >> 3) & 1;
    int lane = (c & 31) + (g << 5);
    return ((K16 * 4 + cblk) << 9) + (lane << 3) + (r & 7);
}

__device__ __forceinline__ float4 relu_add4(float4 a, float4 b) {
    float4 r;
    r.x = fmaxf(a.x + b.x, 0.f); r.y = fmaxf(a.y + b.y, 0.f);
    r.z = fmaxf(a.z + b.z, 0.f); r.w = fmaxf(a.w + b.w, 0.f);
    return r;
}

// ---------------------------------------------------------------------------
// Small fp32 GEMM producer: out = A[16384][K] @ W[K][128]; epilogue splits
// each output into bf16 hi/lo and scatters into the fragment layout.
// ADD2: A := relu(A + A2) elementwise (fused partial-reduce of the hidden).
// ---------------------------------------------------------------------------
template<int K, bool FUSED, bool ADD2>
__global__ __launch_bounds__(256)
void producer_kernel(const float* __restrict__ A,
                     const float* __restrict__ A2,
                     const float* __restrict__ W,
                     const float* __restrict__ Wa,
                     const float* __restrict__ Wb,
                     bf16_t* __restrict__ Bh,
                     bf16_t* __restrict__ Bl)
{
    __shared__ float As[32][128];   // k-major A tile: As[k][r]
    __shared__ float Wsh[32][128];  // Wsh[k][c]
    const int t    = threadIdx.x;
    const int row0 = blockIdx.x * 128;
    const int tc   = t & 15, tr = t >> 4;   // 16x16 thread grid, 8x8 outs each

    float acc[8][8];
    #pragma unroll
    for (int i = 0; i < 8; ++i)
        #pragma unroll
        for (int j = 0; j < 8; ++j) acc[i][j] = 0.f;

    const int ra = t >> 1, ks = (t & 1) << 4;   // A staging: 16 f32/thread
    const int wk = t >> 3, wc = (t & 7) << 4;   // W staging: 16 f32/thread

    for (int k0 = 0; k0 < K; k0 += 32) {
        const float* ap = A + (size_t)(row0 + ra) * K + k0 + ks;
        float4 a0 = *(const float4*)(ap);
        float4 a1 = *(const float4*)(ap + 4);
        float4 a2 = *(const float4*)(ap + 8);
        float4 a3 = *(const float4*)(ap + 12);
        if (ADD2) {
            const float* ap2 = A2 + (size_t)(row0 + ra) * K + k0 + ks;
            a0 = relu_add4(a0, *(const float4*)(ap2));
            a1 = relu_add4(a1, *(const float4*)(ap2 + 4));
            a2 = relu_add4(a2, *(const float4*)(ap2 + 8));
            a3 = relu_add4(a3, *(const float4*)(ap2 + 12));
        }
        float4 w0, w1, w2, w3;
        if (!FUSED) {
            const float* wp = W + (size_t)(k0 + wk) * 128 + wc;
            w0 = *(const float4*)(wp);     w1 = *(const float4*)(wp + 4);
            w2 = *(const float4*)(wp + 8); w3 = *(const float4*)(wp + 12);
        } else {
            const float* wp = (wc < 64) ? (Wa + (size_t)(k0 + wk) * 64 + wc)
                                        : (Wb + (size_t)(k0 + wk) * 64 + (wc - 64));
            w0 = *(const float4*)(wp);     w1 = *(const float4*)(wp + 4);
            w2 = *(const float4*)(wp + 8); w3 = *(const float4*)(wp + 12);
        }
        __syncthreads();   // previous iteration's compute done before overwrite
        {
            float tmp[16] = {a0.x,a0.y,a0.z,a0.w, a1.x,a1.y,a1.z,a1.w,
                             a2.x,a2.y,a2.z,a2.w, a3.x,a3.y,a3.z,a3.w};
            #pragma unroll
            for (int j = 0; j < 16; ++j) As[ks + j][ra] = tmp[j];
            *(float4*)&Wsh[wk][wc     ] = w0;
            *(float4*)&Wsh[wk][wc +  4] = w1;
            *(float4*)&Wsh[wk][wc +  8] = w2;
            *(float4*)&Wsh[wk][wc + 12] = w3;
        }
        __syncthreads();
        #pragma unroll 4
        for (int k = 0; k < 32; ++k) {
            float av[8], wv[8];
            *(float4*)&av[0] = *(const float4*)&As[k][8 * tr];
            *(float4*)&av[4] = *(const float4*)&As[k][8 * tr + 4];
            *(float4*)&wv[0] = *(const float4*)&Wsh[k][8 * tc];
            *(float4*)&wv[4] = *(const float4*)&Wsh[k][8 * tc + 4];
            #pragma unroll
            for (int i = 0; i < 8; ++i)
                #pragma unroll
                for (int j = 0; j < 8; ++j)
                    acc[i][j] = fmaf(av[i], wv[j], acc[i][j]);
        }
    }

    #pragma unroll
    for (int i = 0; i < 8; ++i) {
        int r = row0 + 8 * tr + i;
        #pragma unroll
        for (int j = 0; j < 8; ++j) {
            int c = 8 * tc + j;
            float v = acc[i][j];
            bf16_t h = (bf16_t)v;
            bf16_t l = (bf16_t)(v - (float)h);
            int off = frag_off(r, c);
            Bh[off] = h;
            Bl[off] = l;
        }
    }
}

// ---------------------------------------------------------------------------
// Big kernel: P_kh = adj[rows, kh-half] @ B[kh-half], M-tile 64, K-half 8192.
// grid 512 (256 mt x 2 kh) = 2 blocks/CU, 512 thr (8 waves = 2 row-half x
// 4 col-quadrant). 32 macros of K=256; single-buffer LDS [64][256] hi+lo
// = 64 KB. adj: wave w stages rows w*8..w*8+7, one 1KB dwordx4 burst per
// row per macro (per-wave state identical to R9). Two lgkm-only barriers
// per macro; latency hiding via the other co-resident block.
// LDS swizzle: elem (r,k) at (r<<8) + (((k>>4) ^ (r&15))<<4) + (k&15).
// ---------------------------------------------------------------------------
struct BSet { bf16x8 h[4]; bf16x8 l[4]; };   // 32 VGPRs

__global__ __launch_bounds__(512, 4)
void adj_gemm_kernel(const float* __restrict__ adj,
                     const bf16_t* __restrict__ Bh,
                     const bf16_t* __restrict__ Bl,
                     float* __restrict__ P0,
                     float* __restrict__ P1)
{
    __shared__ __align__(16) bf16_t AsH[64 * 256];   // 32KB
    __shared__ __align__(16) bf16_t AsL[64 * 256];   // 32KB
    const int t    = threadIdx.x;
    const int lane = t & 63;
    const int w    = t >> 6;                 // 0..7
    const int mt   = blockIdx.x >> 1;
    const int kh   = blockIdx.x & 1;
    const int row0 = mt << 6;
    const int hi32 = lane >> 5;
    float* const outP = kh ? P1 : P0;

    // adj staging: wave w stages rows w*8+j (j=0..7), one wave-wide dwordx4
    // burst per row (64 lanes x 16B = 1KB contiguous); macro k-span 256.
    const float* aBase = adj + (size_t)(row0 + (w << 3)) * 16384
                             + (kh << 13) + (lane << 2);

    // LDS write indices: row = w*8+j, elems k = lane*4..+3
    int wIdx[8];
    #pragma unroll
    for (int j = 0; j < 8; ++j) {
        int row = (w << 3) + j;
        wIdx[j] = (row << 8) + ((((lane >> 2) ^ (row & 15)) << 4)
                                + ((lane & 3) << 2));
    }

    // A-frag reads: wave = (row-half rh = w>>2, col-quadrant cq = w&3)
    const int rh    = w >> 2, cq = w & 3;
    const int frow  = (rh << 5) + (lane & 31);
    const int rbase = (frow << 8) + (hi32 << 3);
    const int rx    = frow & 15;

    // B frag per-thread base; sub (K=64) stride = 8192 elems
    const int tb   = (cq << 9) + (lane << 3);
    const int sub0 = kh << 7;                // kh*128 subs

    f32x16 acc;
    #pragma unroll
    for (int i = 0; i < 16; ++i) acc[i] = 0.f;

    f32x4 ar[8];
    BSet S;

    auto loadAdj = [&](int mac) {
        const float* p = aBase + (mac << 8);
        #pragma unroll
        for (int j = 0; j < 8; ++j)
            ar[j] = __builtin_nontemporal_load((const f32x4*)(p + (size_t)j * 16384));
    };
    auto cvtWrite = [&]() {
        #pragma unroll
        for (int j = 0; j < 8; ++j) {
            bf16x4 hv, lv;
            #pragma unroll
            for (int e = 0; e < 4; ++e) {
                float v = ar[j][e];
                bf16_t h = (bf16_t)v;
                hv[e] = h;
                lv[e] = (bf16_t)(v - (float)h);
            }
            *(bf16x4*)&AsH[wIdx[j]] = hv;
            *(bf16x4*)&AsL[wIdx[j]] = lv;
        }
    };
    auto loadB = [&](int sub) {
        const size_t base = ((size_t)sub << 13) + tb;
        #pragma unroll
        for (int s = 0; s < 4; ++s) {
            S.h[s] = *(const bf16x8*)(Bh + base + (s << 11));
            S.l[s] = *(const bf16x8*)(Bl + base + (s << 11));
        }
    };
    auto computeS = [&](int s) {
        #pragma unroll
        for (int k16 = 0; k16 < 4; ++k16) {
            const int u  = (s << 2) + k16;
            const int id = rbase + ((u ^ rx) << 4);
            bf16x8 ah = *(const bf16x8*)&AsH[id];
            bf16x8 al = *(const bf16x8*)&AsL[id];
            MFMA3(acc, ah, S.h[k16]);
            MFMA3(acc, ah, S.l[k16]);
            MFMA3(acc, al, S.h[k16]);
        }
    };

    // lgkm-only barrier: ds ops drained; register-dest global loads stay in
    // flight across the barrier (counted vmcnt by compiler).
#define SYNC_LDS() do { asm volatile("s_waitcnt lgkmcnt(0)" ::: "memory"); \
                        __builtin_amdgcn_s_barrier(); } while (0)

    loadAdj(0);
    for (int m = 0; m < 32; ++m) {
        cvtWrite();                          // waits ar = adj(m)
        SYNC_LDS();                          // staged tile visible
        const int sb = sub0 + (m << 2);
        loadB(sb + 0);
        if (m < 31) loadAdj(m + 1);          // in flight across the macro
        computeS(0);
        loadB(sb + 1);  computeS(1);
        loadB(sb + 2);  computeS(2);
        loadB(sb + 3);  computeS(3);
        SYNC_LDS();                          // reads done before overwrite
    }
#undef SYNC_LDS

    // C write: col = cq*32 + lane&31, row = (q&3) + 8*(q>>2) + 4*hi32
    const int col = (cq << 5) + (lane & 31);
    const int rb  = row0 + (rh << 5) + (hi32 << 2);
    #pragma unroll
    for (int q = 0; q < 16; ++q) {
        int r = rb + (q & 3) + ((q >> 2) << 3);
        outP[(size_t)r * 128 + col] = acc[q];
    }
}

// ---------------------------------------------------------------------------
// Final: T = T0+T1 ([16384][128], Z cols 0-63 | logstd cols 64-127);
// mean = Z@Wp + bp; out = noise*exp(min(logstd,10)) + mean
// ---------------------------------------------------------------------------
__global__ __launch_bounds__(256)
void final_kernel(const float* __restrict__ T0,
                  const float* __restrict__ T1,
                  const float* __restrict__ Wp,
                  const float* __restrict__ bp,
                  const float* __restrict__ noise,
                  float* __restrict__ out)
{
    __shared__ float Wps[64][64];
    __shared__ float Ts[64][64];
    const int t = threadIdx.x;
    const int row0 = blockIdx.x * 64;
    {
        int k = t >> 2, c0 = (t & 3) << 4;
        #pragma unroll
        for (int i = 0; i < 4; ++i)
            *(float4*)&Wps[k][c0 + 4 * i] = *(const float4*)&Wp[(size_t)k * 64 + c0 + 4 * i];
        #pragma unroll
        for (int i = 0; i < 4; ++i) {
            float4 z0 = *(const float4*)&T0[(size_t)(row0 + k) * 128 + c0 + 4 * i];
            float4 z1 = *(const float4*)&T1[(size_t)(row0 + k) * 128 + c0 + 4 * i];
            float4 zs; zs.x = z0.x + z1.x; zs.y = z0.y + z1.y;
            zs.z = z0.z + z1.z; zs.w = z0.w + z1.w;
            *(float4*)&Ts[k][c0 + 4 * i] = zs;
        }
    }
    __syncthreads();

    const int r  = t >> 2;
    const int c0 = (t & 3) << 4;
    float acc[16];
    #pragma unroll
    for (int j = 0; j < 16; ++j) acc[j] = bp[c0 + j];
    for (int k = 0; k < 64; ++k) {
        float a = Ts[r][k];
        #pragma unroll
        for (int j = 0; j < 16; ++j) acc[j] = fmaf(a, Wps[k][c0 + j], acc[j]);
    }
    const int grow = row0 + r;
    #pragma unroll
    for (int j = 0; j < 16; ++j) {
        size_t li = (size_t)grow * 128 + 64 + c0 + j;
        float ls = T0[li] + T1[li];
        ls = fminf(ls, 10.0f);
        out[(size_t)grow * 64 + c0 + j] =
            noise[(size_t)grow * 64 + c0 + j] * __expf(ls) + acc[j];
    }
}

// ---------------------------------------------------------------------------
extern "C" void kernel_launch(void* const* d_in, const int* in_sizes, int n_in,
                              void* d_out, int out_size, void* d_ws, size_t ws_size,
                              hipStream_t stream) {
    const float* X     = (const float*)d_in[0];
    const float* adj   = (const float*)d_in[1];
    const float* W1    = (const float*)d_in[2];
    const float* Wm    = (const float*)d_in[3];
    const float* Wsv   = (const float*)d_in[4];
    const float* Wp    = (const float*)d_in[5];
    const float* bp    = (const float*)d_in[6];
    const float* noise = (const float*)d_in[7];
    float* out = (float*)d_out;

    char* ws = (char*)d_ws;
    bf16_t* Bh = (bf16_t*)ws;                     // 4 MB
    bf16_t* Bl = (bf16_t*)(ws + (4u << 20));      // 4 MB
    float*  P0 = (float*)(ws + (8u << 20));       // 8 MB partial (kh=0)
    float*  P1 = (float*)(ws + (16u << 20));      // 8 MB partial (kh=1)

    // S1: B1 = fragsplit((X @ W1)^T)
    producer_kernel<256, false, false><<<128, 256, 0, stream>>>(
        X, nullptr, W1, nullptr, nullptr, Bh, Bl);
    // S2: hidden partials: P_kh = adj[:, kh-half] @ B1[kh-half]
    adj_gemm_kernel<<<512, 512, 0, stream>>>(adj, Bh, Bl, P0, P1);
    // S3: B2 = fragsplit((relu(P0+P1) @ [Wm|Ws])^T)   (reduce+relu fused)
    producer_kernel<128, true, true><<<128, 256, 0, stream>>>(
        P0, P1, nullptr, Wm, Wsv, Bh, Bl);
    // S4: T partials
    adj_gemm_kernel<<<512, 512, 0, stream>>>(adj, Bh, Bl, P0, P1);
    // S5: epilogue (T = P0+P1 summed on the fly)
    final_kernel<<<256, 256, 0, stream>>>(P0, P1, Wp, bp, noise, out);
}